// Round 3
// baseline (413.982 us; speedup 1.0000x reference)
//
#include <hip/hip_runtime.h>

// Problem constants (from reference): B=4, NV=50000, NRINGS=3, NDIRS=16, NF=16
// Dtypes (verified by rounds 0-2): ALL float tensors are float32, expmap int32,
// OUTPUT float32. (R1's inf = f32 bits read as bf16; R2's absmax==max|ref| =
// bf16-packed writes read back as f32.)
#define NBATCH 4
#define NV     50000
#define NRINGS 3
#define NDIRS  16
#define NF     16
#define VPB    16          // vertices per block (256 threads = 16 v x 16 f)
#define YLS    148         // per-vertex yl stride in floats (144 + 4 pad)
#define KTS    20          // kt dd-stride (16 + 4 pad, keeps 16B alignment)

__global__ __launch_bounds__(256, 4)
void input3d_kernel(const float* __restrict__ bp,     // (B,NV,3) f32
                    const float* __restrict__ fr,     // (B,NV,3,3) f32
                    const int2*  __restrict__ em,     // (B,NV,3,16,2) int32 pairs
                    const float* __restrict__ kw,     // (3,16,3,16) f32
                    const float* __restrict__ bias,   // (16) f32
                    float*       __restrict__ out)    // (B,NV,16,16) f32
{
    // kt: [(r*3+c)*16+f][dd pad20]  = 2880 f32 = 11520 B
    __shared__ __align__(16) float kt[NRINGS * 3 * NF * KTS];
    // yl: [v][c*48 + r*16 + d], stride 148 = 2368 f32 = 9472 B
    __shared__ __align__(16) float yl[VPB * YLS];
    // ostage: [v*256 + d*16 + f] = 4096 f32 = 16384 B
    __shared__ __align__(16) float ost[VPB * NDIRS * NF];

    const int tid = threadIdx.x;
    const int bv0 = blockIdx.x * VPB;   // flattened (b*NV+v) base for this block

    // ---- load conv kernel into LDS, transposed to [rc][f][dd] ----
    for (int i = tid; i < NRINGS * NDIRS * 3 * NF; i += 256) {
        // source i = ((r*16+dd)*3 + c)*16 + f
        int f  = i & 15;
        int c  = (i >> 4) % 3;
        int dd = (i / 48) & 15;
        int r  = i / 768;
        kt[((r * 3 + c) * 16 + f) * KTS + dd] = kw[i];
    }

    // ---- stage rotated local coords: 768 points/block, 3 per thread ----
    #pragma unroll
    for (int k = 0; k < 3; ++k) {
        int p   = tid + k * 256;        // 0..767
        int v   = p / 48;               // local vertex
        int i48 = p - v * 48;           // r*16 + d
        int bv  = bv0 + v;
        int2 e  = em[bv * 48 + i48];    // (.x=batch, .y=vertex)
        int nb  = e.x * NV + e.y;       // neighbor flattened index
        float cx = bp[bv * 3 + 0];
        float cy = bp[bv * 3 + 1];
        float cz = bp[bv * 3 + 2];
        float d0 = bp[nb * 3 + 0] - cx;
        float d1 = bp[nb * 3 + 1] - cy;
        float d2 = bp[nb * 3 + 2] - cz;
        const float* F = fr + (size_t)bv * 9;
        #pragma unroll
        for (int c = 0; c < 3; ++c) {
            // einsum 'bvkl,bvrdl->bvrdk': yl[k=c] = sum_l F[c,l]*(p[l]-ctr[l])
            float yv = F[c * 3 + 0] * d0
                     + F[c * 3 + 1] * d1
                     + F[c * 3 + 2] * d2;
            yl[v * YLS + c * 48 + i48] = yv;
        }
    }
    __syncthreads();

    // ---- compute: thread = (vloc, f); acc over all 16 d ----
    const int vloc = tid >> 4;
    const int f    = tid & 15;
    float acc[16];
    #pragma unroll
    for (int d = 0; d < 16; ++d) acc[d] = 0.f;

    const float* ylv = &yl[vloc * YLS];
    #pragma unroll 1
    for (int rc = 0; rc < 9; ++rc) {            // rc = r*3 + c
        int r = rc / 3;
        int c = rc - r * 3;
        float ylr[16];
        const float4* y4 = (const float4*)(ylv + c * 48 + r * 16);
        *(float4*)&ylr[0]  = y4[0];
        *(float4*)&ylr[4]  = y4[1];
        *(float4*)&ylr[8]  = y4[2];
        *(float4*)&ylr[12] = y4[3];
        float kf[16];
        const float4* k4 = (const float4*)&kt[(rc * 16 + f) * KTS];
        *(float4*)&kf[0]  = k4[0];
        *(float4*)&kf[4]  = k4[1];
        *(float4*)&kf[8]  = k4[2];
        *(float4*)&kf[12] = k4[3];
        #pragma unroll
        for (int dd = 0; dd < 16; ++dd) {
            float kv = kf[dd];
            #pragma unroll
            for (int d = 0; d < 16; ++d)
                acc[d] = fmaf(ylr[(d + dd) & 15], kv, acc[d]);
        }
    }

    // ---- bias + relu -> LDS transpose to (v,d,f) layout ----
    float bsf = bias[f];
    #pragma unroll
    for (int d = 0; d < 16; ++d) {
        float o = acc[d] + bsf;
        ost[vloc * 256 + d * 16 + f] = o > 0.f ? o : 0.f;
    }
    __syncthreads();

    // ---- each thread stores 16 consecutive f32 (4x float4), coalesced ----
    const float4* s4 = (const float4*)&ost[tid * 16];
    float4* dst = (float4*)(out + (size_t)bv0 * 256 + (size_t)tid * 16);
    dst[0] = s4[0];
    dst[1] = s4[1];
    dst[2] = s4[2];
    dst[3] = s4[3];
}

extern "C" void kernel_launch(void* const* d_in, const int* in_sizes, int n_in,
                              void* d_out, int out_size, void* d_ws, size_t ws_size,
                              hipStream_t stream) {
    const float* bp   = (const float*)d_in[0];
    const float* fr   = (const float*)d_in[1];
    const int2*  em   = (const int2*)d_in[2];
    const float* kw   = (const float*)d_in[3];
    const float* bias = (const float*)d_in[4];
    float* out = (float*)d_out;

    const int total_bv = NBATCH * NV;          // 200000
    const int grid = total_bv / VPB;           // 12500 blocks
    input3d_kernel<<<grid, 256, 0, stream>>>(bp, fr, em, kw, bias, out);
}

// Round 5
// 367.379 us; speedup vs baseline: 1.1269x; 1.1269x over previous
//
#include <hip/hip_runtime.h>
#include <hip/hip_bf16.h>

// B=4, NV=50000, NRINGS=3, NDIRS=16, NF=16. All f32 except expmap(int32).
// MFMA formulation: per vertex D[16d x 16f] = A[16d x 144k] * W[144k x 16f],
// k = dd*9 + q, q = r*3+c.  A[m][k] = yl3[9m+k] where yl3[i*9+q] = yl[q][i%16]
// (i=0..30, direction-duplicated). Two LDS copies (shift-by-1) fix the
// odd-m 2-byte misalignment so every lane reads 4B-aligned dwords.
// R5 fixes vs R4: (1) __align__(16) on yls — ushort array had alignof 2, a
// 2-mod-4 LDS base misaligns every ds_read_b32 (the R4 failure theory);
// (2) zero the K-pad tail (yl3[279..294] / shifted 278..293) so k=144..159
// garbage can't inject Inf/NaN through the zero-W MFMA tail.
#define NBATCH 4
#define NV     50000
#define VPB    16          // vertices per block (4 waves x 4 vertices)
#define VST    304         // per-vertex buffer stride in bf16 elems (need >=296, even)

typedef __attribute__((ext_vector_type(8))) short short8;
typedef __attribute__((ext_vector_type(4))) float floatx4;

__global__ __launch_bounds__(256, 4)
void input3d_mfma(const float* __restrict__ bp,     // (B,NV,3)
                  const float* __restrict__ fr,     // (B,NV,3,3)
                  const int2*  __restrict__ em,     // (B,NV,3,16) int pairs
                  const float* __restrict__ kw,     // (3,16,3,16)
                  const float* __restrict__ bias,   // (16)
                  float*       __restrict__ out)    // (B,NV,16,16)
{
    __shared__ __align__(16) unsigned short yls[VPB * 2 * VST];   // 19456 B

    const int tid  = threadIdx.x;
    const int bv0  = blockIdx.x * VPB;
    const int lane = tid & 63;
    const int wid  = tid >> 6;
    const int fcol = lane & 15;   // = f for W/D cols, = m(d) for A rows
    const int quad = lane >> 4;

    // ---- zero the K-pad tails (disjoint from all staged addresses) ----
    // even buf: valid data ends at 278, reads go to 294 -> zero 279..303
    // shifted : valid data ends at VST+277, reads to VST+293 -> zero VST+278..VST+303
    for (int i = tid; i < VPB * 51; i += 256) {
        int v = i / 51;
        int w = i - v * 51;
        int off = (w < 25) ? (279 + w) : (VST + 278 + (w - 25));
        yls[v * 2 * VST + off] = 0;
    }

    // ---- W fragments (B-operand), in registers, shared by all vertices ----
    // lane holds W[k = kc*32 + quad*8 + j][f = lane&15]; k>=144 -> 0 (K pad)
    union WU { short s[8]; short8 v; };
    WU wf[5];
    #pragma unroll
    for (int kc = 0; kc < 5; ++kc) {
        #pragma unroll
        for (int j = 0; j < 8; ++j) {
            int k = kc * 32 + quad * 8 + j;
            unsigned short b = 0;
            if (k < 144) {
                int dd = k / 9;
                int q  = k - dd * 9;
                int r  = q / 3;
                int c  = q - r * 3;
                __hip_bfloat16 h = __float2bfloat16(kw[((r * 16 + dd) * 3 + c) * 16 + fcol]);
                __builtin_memcpy(&b, &h, 2);
            }
            wf[kc].s[j] = (short)b;
        }
    }
    const float bsf = bias[fcol];

    // ---- stage gathered+rotated coords as bf16 circulant-linear layout ----
    #pragma unroll
    for (int t = 0; t < 3; ++t) {
        int p   = tid + t * 256;        // 0..767 = 16 v x 48 (r,dir)
        int v   = p / 48;
        int i48 = p - v * 48;
        int r   = i48 >> 4;
        int dir = i48 & 15;
        int bv  = bv0 + v;
        int2 e  = em[bv * 48 + i48];
        int nb  = e.x * NV + e.y;
        float dx = bp[nb * 3 + 0] - bp[bv * 3 + 0];
        float dy = bp[nb * 3 + 1] - bp[bv * 3 + 1];
        float dz = bp[nb * 3 + 2] - bp[bv * 3 + 2];
        const float* F = fr + (size_t)bv * 9;
        unsigned short* buf = &yls[v * 2 * VST];
        #pragma unroll
        for (int c = 0; c < 3; ++c) {
            float yv = F[c * 3 + 0] * dx + F[c * 3 + 1] * dy + F[c * 3 + 2] * dz;
            __hip_bfloat16 h = __float2bfloat16(yv);
            unsigned short us;
            __builtin_memcpy(&us, &h, 2);
            int q  = r * 3 + c;
            int e1 = dir * 9 + q;              // element index in yl3
            buf[e1] = us;                      // even-aligned copy
            if (e1 > 0) buf[VST + e1 - 1] = us; // shifted copy for odd-m lanes
            if (dir < 15) {                    // duplicate dirs 0..14 at i+16
                buf[e1 + 144] = us;            // (dir+16)*9+q = e1+144
                buf[VST + e1 + 143] = us;
            }
        }
    }
    __syncthreads();

    // ---- per wave: 4 vertices, 5 MFMA each (K=160, last chunk half zero-W) ----
    floatx4 acc[4] = {{0.f,0.f,0.f,0.f},{0.f,0.f,0.f,0.f},
                      {0.f,0.f,0.f,0.f},{0.f,0.f,0.f,0.f}};
    const unsigned short* abase[4];
    #pragma unroll
    for (int i = 0; i < 4; ++i) {
        int v = wid * 4 + i;
        // odd m uses the shifted buffer: (base + s) stays even -> 4B aligned
        abase[i] = &yls[v * 2 * VST + ((fcol & 1) ? (VST - 1) : 0) + 9 * fcol];
    }
    #pragma unroll
    for (int kc = 0; kc < 5; ++kc) {
        const int s = kc * 32 + quad * 8;
        #pragma unroll
        for (int i = 0; i < 4; ++i) {
            const unsigned int* pa = (const unsigned int*)(abase[i] + s);
            union { unsigned int u[4]; short8 s8; } a;
            a.u[0] = pa[0]; a.u[1] = pa[1]; a.u[2] = pa[2]; a.u[3] = pa[3];
            acc[i] = __builtin_amdgcn_mfma_f32_16x16x32_bf16(a.s8, wf[kc].v, acc[i], 0, 0, 0);
        }
    }

    // ---- epilogue: C layout col=lane&15=f, row=quad*4+reg=d -> direct store ----
    #pragma unroll
    for (int i = 0; i < 4; ++i) {
        int vg = bv0 + wid * 4 + i;
        float* ob = out + (size_t)vg * 256;
        #pragma unroll
        for (int rr = 0; rr < 4; ++rr) {
            float o = acc[i][rr] + bsf;
            o = o > 0.f ? o : 0.f;
            ob[(quad * 4 + rr) * 16 + fcol] = o;
        }
    }
}

extern "C" void kernel_launch(void* const* d_in, const int* in_sizes, int n_in,
                              void* d_out, int out_size, void* d_ws, size_t ws_size,
                              hipStream_t stream) {
    const float* bp   = (const float*)d_in[0];
    const float* fr   = (const float*)d_in[1];
    const int2*  em   = (const int2*)d_in[2];
    const float* kw   = (const float*)d_in[3];
    const float* bias = (const float*)d_in[4];
    float* out = (float*)d_out;

    const int total_bv = NBATCH * NV;          // 200000
    const int grid = total_bv / VPB;           // 12500 blocks
    input3d_mfma<<<grid, 256, 0, stream>>>(bp, fr, em, kw, bias, out);
}

// Round 6
// 351.796 us; speedup vs baseline: 1.1768x; 1.0443x over previous
//
#include <hip/hip_runtime.h>
#include <hip/hip_bf16.h>

// B=4, NV=50000, NRINGS=3, NDIRS=16, NF=16. All f32 except expmap(int32).
// MFMA: per vertex D[16d x 16f] = A[16d x 144k] * W[144k x 16f], k = dd*9 + q.
// A[m][k] = yl3[9m+k], yl3[i*9+q] = yl[q][i%16] (dir-duplicated circulant).
// 2 LDS copies (shift-by-1) give 4B alignment for both m-parities (R5-proven).
// R6 vs R5: (1) W fragments prebuilt by a pre-kernel into d_ws (was ~150 VALU
// + 40 scalar loads per thread, identical across all 12500 blocks);
// (2) staging thread=(v,dir): 9 consecutive elements -> packed b32 writes
// (20 vs 36 LDS insts), frame/center loaded once; (3) exact K=144: chunk 4
// valid k (128..143) lives in quads 0-1 only -> quads 2-3 zero A regs, no
// LDS zero-tail loop.
#define NBATCH 4
#define NV     50000
#define VPB    16          // vertices per block (4 waves x 4 vertices)
#define VST    304         // per-copy stride in bf16 elems (even, >=296)

typedef __attribute__((ext_vector_type(8))) short short8;
typedef __attribute__((ext_vector_type(4))) float floatx4;

// ---- pre-kernel: build per-lane W fragments (bf16) into d_ws ----
// layout: lane*40 + kc*8 ushorts (16B per chunk, 80B per lane, 5120B total)
__global__ void build_wfrag(const float* __restrict__ kw,
                            unsigned short* __restrict__ wbuf) {
    const int lane = threadIdx.x;      // 0..63
    const int fcol = lane & 15;
    const int quad = lane >> 4;
    #pragma unroll
    for (int kc = 0; kc < 5; ++kc) {
        unsigned short v[8];
        #pragma unroll
        for (int j = 0; j < 8; ++j) {
            int k = kc * 32 + quad * 8 + j;
            unsigned short b = 0;
            if (k < 144) {
                int dd = k / 9;
                int q  = k - dd * 9;
                int r  = q / 3;
                int c  = q - r * 3;
                __hip_bfloat16 h = __float2bfloat16(kw[((r * 16 + dd) * 3 + c) * 16 + fcol]);
                __builtin_memcpy(&b, &h, 2);
            }
            v[j] = b;
        }
        __builtin_memcpy(wbuf + lane * 40 + kc * 8, v, 16);
    }
}

__global__ __launch_bounds__(256, 4)
void input3d_mfma(const float* __restrict__ bp,     // (B,NV,3)
                  const float* __restrict__ fr,     // (B,NV,3,3)
                  const int2*  __restrict__ em,     // (B,NV,3,16) int pairs
                  const unsigned short* __restrict__ wbuf, // prebuilt W frags
                  const float* __restrict__ bias,   // (16)
                  float*       __restrict__ out)    // (B,NV,16,16)
{
    __shared__ __align__(16) unsigned short yls[VPB * 2 * VST];   // 19456 B

    const int tid  = threadIdx.x;
    const int bv0  = blockIdx.x * VPB;
    const int lane = tid & 63;
    const int wid  = tid >> 6;
    const int fcol = lane & 15;
    const int quad = lane >> 4;

    // ---- load prebuilt W fragments: 5 x dwordx4 ----
    union WU { unsigned short s[8]; short8 v; };
    WU wf[5];
    const unsigned short* wl = wbuf + lane * 40;
    #pragma unroll
    for (int kc = 0; kc < 5; ++kc)
        __builtin_memcpy(&wf[kc].s[0], wl + kc * 8, 16);
    const float bsf = bias[fcol];

    // ---- staging: thread = (v = tid>>4, dir = tid&15) ----
    {
        const int v   = tid >> 4;
        const int dir = tid & 15;
        const int bv  = bv0 + v;
        float F[9];
        __builtin_memcpy(&F[0], fr + (size_t)bv * 9, 16);
        __builtin_memcpy(&F[4], fr + (size_t)bv * 9 + 4, 16);
        F[8] = fr[(size_t)bv * 9 + 8];
        const float c0 = bp[bv * 3 + 0];
        const float c1 = bp[bv * 3 + 1];
        const float c2 = bp[bv * 3 + 2];

        unsigned short val[9];
        #pragma unroll
        for (int r = 0; r < 3; ++r) {
            int2 e  = em[bv * 48 + r * 16 + dir];
            int nb  = e.x * NV + e.y;
            float dx = bp[nb * 3 + 0] - c0;
            float dy = bp[nb * 3 + 1] - c1;
            float dz = bp[nb * 3 + 2] - c2;
            #pragma unroll
            for (int c = 0; c < 3; ++c) {
                float yv = F[c * 3 + 0] * dx + F[c * 3 + 1] * dy + F[c * 3 + 2] * dz;
                __hip_bfloat16 h = __float2bfloat16(yv);
                unsigned short us;
                __builtin_memcpy(&us, &h, 2);
                val[r * 3 + c] = us;
            }
        }

        // packed 9-element group writes (4 x b32 + 1 x u16 per group)
        unsigned short* buf = &yls[v * 2 * VST];
        unsigned int pe[4], po[4];
        #pragma unroll
        for (int i = 0; i < 4; ++i) {
            pe[i] = (unsigned int)val[2 * i]     | ((unsigned int)val[2 * i + 1] << 16);
            po[i] = (unsigned int)val[2 * i + 1] | ((unsigned int)val[2 * i + 2] << 16);
        }
        const int n0 = dir * 9;
        // even-start group: dwords at s, tail u16 at s+8
        auto storeE = [&](int s) {
            unsigned int* p = (unsigned int*)(buf + s);
            p[0] = pe[0]; p[1] = pe[1]; p[2] = pe[2]; p[3] = pe[3];
            buf[s + 8] = val[8];
        };
        // odd-start group: head u16 at s, dwords at s+1
        auto storeO = [&](int s) {
            buf[s] = val[0];
            unsigned int* p = (unsigned int*)(buf + s + 1);
            p[0] = po[0]; p[1] = po[1]; p[2] = po[2]; p[3] = po[3];
        };
        if (dir & 1) {                 // n0 odd
            storeO(n0);
            storeE(VST + n0 - 1);
            if (dir < 15) { storeO(n0 + 144); storeE(VST + n0 + 143); }
        } else {                       // n0 even
            storeE(n0);
            storeO(VST + n0 - 1);
            if (dir < 15) { storeE(n0 + 144); storeO(VST + n0 + 143); }
        }
    }
    __syncthreads();

    // ---- per wave: 4 vertices, 5 MFMA each (K=144 exact) ----
    floatx4 acc[4] = {{0.f,0.f,0.f,0.f},{0.f,0.f,0.f,0.f},
                      {0.f,0.f,0.f,0.f},{0.f,0.f,0.f,0.f}};
    const unsigned short* abase[4];
    #pragma unroll
    for (int i = 0; i < 4; ++i) {
        int v = wid * 4 + i;
        abase[i] = &yls[v * 2 * VST + ((fcol & 1) ? (VST - 1) : 0) + 9 * fcol];
    }
    #pragma unroll
    for (int kc = 0; kc < 4; ++kc) {
        const int s = kc * 32 + quad * 8;
        #pragma unroll
        for (int i = 0; i < 4; ++i) {
            const unsigned int* pa = (const unsigned int*)(abase[i] + s);
            union { unsigned int u[4]; short8 s8; } a;
            a.u[0] = pa[0]; a.u[1] = pa[1]; a.u[2] = pa[2]; a.u[3] = pa[3];
            acc[i] = __builtin_amdgcn_mfma_f32_16x16x32_bf16(a.s8, wf[kc].v, acc[i], 0, 0, 0);
        }
    }
    {   // chunk 4: k = 128 + quad*8 + j; valid k<144 only for quads 0,1.
        const int s = 128 + quad * 8;
        #pragma unroll
        for (int i = 0; i < 4; ++i) {
            union { unsigned int u[4]; short8 s8; } a;
            if (quad < 2) {
                const unsigned int* pa = (const unsigned int*)(abase[i] + s);
                a.u[0] = pa[0]; a.u[1] = pa[1]; a.u[2] = pa[2]; a.u[3] = pa[3];
            } else {
                a.u[0] = 0; a.u[1] = 0; a.u[2] = 0; a.u[3] = 0;
            }
            acc[i] = __builtin_amdgcn_mfma_f32_16x16x32_bf16(a.s8, wf[4].v, acc[i], 0, 0, 0);
        }
    }

    // ---- epilogue: C layout col=lane&15=f, row=quad*4+reg=d -> direct store ----
    #pragma unroll
    for (int i = 0; i < 4; ++i) {
        int vg = bv0 + wid * 4 + i;
        float* ob = out + (size_t)vg * 256;
        #pragma unroll
        for (int rr = 0; rr < 4; ++rr) {
            float o = acc[i][rr] + bsf;
            o = o > 0.f ? o : 0.f;
            ob[(quad * 4 + rr) * 16 + fcol] = o;
        }
    }
}

extern "C" void kernel_launch(void* const* d_in, const int* in_sizes, int n_in,
                              void* d_out, int out_size, void* d_ws, size_t ws_size,
                              hipStream_t stream) {
    const float* bp   = (const float*)d_in[0];
    const float* fr   = (const float*)d_in[1];
    const int2*  em   = (const int2*)d_in[2];
    const float* kw   = (const float*)d_in[3];
    const float* bias = (const float*)d_in[4];
    float* out = (float*)d_out;
    unsigned short* wbuf = (unsigned short*)d_ws;   // 5120 B used

    build_wfrag<<<1, 64, 0, stream>>>(kw, wbuf);

    const int total_bv = NBATCH * NV;          // 200000
    const int grid = total_bv / VPB;           // 12500 blocks
    input3d_mfma<<<grid, 256, 0, stream>>>(bp, fr, em, wbuf, bias, out);
}